// Round 9
// baseline (241.152 us; speedup 1.0000x reference)
//
#include <hip/hip_runtime.h>

#define SEQ   2048
#define BATCH 4
#define NH    16
#define DM    1024
#define MTOT  (BATCH*SEQ)   // 8192

typedef unsigned short u16;
typedef unsigned int   u32;
typedef __attribute__((ext_vector_type(8)))  __bf16 bf16x8;
typedef __attribute__((ext_vector_type(4)))  float  f32x4;
typedef __attribute__((ext_vector_type(16))) float  f32x16;
typedef __attribute__((address_space(1))) u32 as1_u32;
typedef __attribute__((address_space(3))) u32 as3_u32;

__device__ __forceinline__ u16 f2bf(float f) {
  union { float f; u32 u; } c; c.f = f;
  return (u16)((c.u + 0x7fffu + ((c.u >> 16) & 1u)) >> 16);
}

__global__ void cast_bf16_k(const float* __restrict__ in, u16* __restrict__ out, int n4) {
  int i = blockIdx.x * blockDim.x + threadIdx.x;
  if (i < n4) {
    float4 v = reinterpret_cast<const float4*>(in)[i];
    ushort4 o;
    o.x = f2bf(v.x); o.y = f2bf(v.y); o.z = f2bf(v.z); o.w = f2bf(v.w);
    reinterpret_cast<ushort4*>(out)[i] = o;
  }
}

__global__ void rope_tab_k(const int* __restrict__ pos, float2* __restrict__ tab) {
  int i = blockIdx.x * blockDim.x + threadIdx.x;  // s*32 + j
  if (i < SEQ * 32) {
    int s = i >> 5, j = i & 31;
    float p = (float)pos[s];
    float fr = powf(10000.f, -(float)j / 32.f);
    float a = p * fr;
    tab[i] = make_float2(cosf(a), sinf(a));
  }
}

// ---------------------------------------------------------------------------
// 256x256x(BK=64) 8-wave deep-pipelined GEMM (T2+T3+T4+T5 stack).
// C = A @ Bt^T. A [M][1024] bf16, Bt [N][1024] bf16 (row-major over K).
// 512 thr = 8 waves (2M x 4N); per-wave 128x64 out = acc[8][4] f32x4.
// LDS 128 KiB: A/B x 2 dbuf x 2 halves x (128 rows x 64 cols bf16), rows 128 B,
// 16B-slot swizzle slot^=(row&7) (both sides: pre-swizzled global src + read).
// 4 phases/K-tile (one acc quadrant, 16 MFMA each); 1 half-tile staged/phase;
// counted vmcnt(4) once per K-tile; raw s_barrier (never __syncthreads: that
// drains vmcnt); setprio around MFMA; sched_barrier after lgkmcnt (rule #18).
// Stage order: ph0:A1(t+1) ph1:B0(t+1) ph2:B1(t+1) ph3:A0(t+2)  [A0(t+1) came
// from (t-1)ph3]. At ph0-top vmcnt(4) leaves {A0,A1}(t+1) in flight; everything
// older (tile t's 4 halves) is complete. Write-after-read: A0(t+2) targets buf
// cur whose A-half0 was last ds_read at ph2 (lgkmcnt(0) before ph2 MFMA), and
// ph3 begins after ph2's end barrier.
// EPI 1: z=n0>>10 -> RoPE -> Qh/Kh [B,H,S,64] (+Q pre-scale), z=2 -> Vt [B,H,64,S].
// EPI 0: fp32 store to outF [M][1024].
// ---------------------------------------------------------------------------
template<int EPI>
__global__ __launch_bounds__(512, 1)
void gemm8(const u16* __restrict__ A,
           const u16* __restrict__ B0, const u16* __restrict__ B1, const u16* __restrict__ B2,
           float* __restrict__ outF,
           u16* __restrict__ Qh, u16* __restrict__ Kh, u16* __restrict__ Vt,
           const float2* __restrict__ tab) {
  const int K = DM;
  const int NT = K / 64;                 // 16 K-tiles
  __shared__ u16 ls[65536];              // 128 KiB
  char* lsb = (char*)ls;
  const int t = threadIdx.x, lane = t & 63, wid = t >> 6;
  const int wr = wid >> 2, wc = wid & 3;
  const int n0 = blockIdx.x * 256, m0 = blockIdx.y * 256;
  const int z = (EPI == 1) ? (n0 >> 10) : 0;
  const int nb = (EPI == 1) ? (n0 & 1023) : n0;
  const u16* Bt = (EPI == 1) ? ((z == 0) ? B0 : (z == 1 ? B1 : B2)) : B0;

  f32x4 acc[8][4] = {};

  // stage half-tile: hsel 0/1 = A half, 2/3 = B half; 2 gload_lds per thread
#define STAGEH(buf, hsel, kt)                                                       \
  {                                                                                 \
    _Pragma("unroll")                                                               \
    for (int hh = 0; hh < 2; ++hh) {                                                \
      const int idx = hh * 512 + t;                                                 \
      const int row = idx >> 3, slot = idx & 7;                                     \
      const int sg = slot ^ (row & 7);                                              \
      const u16* src = ((hsel) < 2)                                                 \
        ? A  + (size_t)(m0 + (hsel) * 128 + row) * K + (kt) * 64 + sg * 8           \
        : Bt + (size_t)(nb + ((hsel) - 2) * 128 + row) * K + (kt) * 64 + sg * 8;    \
      char* dst = lsb + (((hsel) < 2) ? 0 : 65536) + (buf) * 32768 +                \
                  (((hsel) & 1) * 16384) + idx * 16;                                \
      __builtin_amdgcn_global_load_lds((const as1_u32*)src, (as3_u32*)dst, 16, 0, 0); \
    }                                                                               \
  }

  // frag ds_reads (swizzled): A rows wr*128 + mh*64 + mt*16 + (lane&15)
  bf16x8 af[4][2];   // current mhalf
  bf16x8 bfr[2][2][2];  // [nhalf][nt][kk], both halves live
  const int lslot = lane >> 4;       // 0..3
  const int lswz = lane & 7;
#define READ_A(buf, mh)                                                             \
  _Pragma("unroll")                                                                 \
  for (int mt = 0; mt < 4; ++mt)                                                    \
    _Pragma("unroll")                                                               \
    for (int kk = 0; kk < 2; ++kk) {                                                \
      const int r = (mh) * 64 + mt * 16 + (lane & 15);                              \
      af[mt][kk] = *(const bf16x8*)(lsb + (buf) * 32768 + wr * 16384 + r * 128 +    \
                                    ((((kk << 2) + lslot) ^ lswz) << 4));           \
    }
#define READ_B(buf, nh)                                                             \
  _Pragma("unroll")                                                                 \
  for (int nt = 0; nt < 2; ++nt)                                                    \
    _Pragma("unroll")                                                               \
    for (int kk = 0; kk < 2; ++kk) {                                                \
      const int r = (wc & 1) * 64 + (nh) * 32 + nt * 16 + (lane & 15);              \
      bfr[nh][nt][kk] = *(const bf16x8*)(lsb + 65536 + (buf) * 32768 +              \
                                         (wc >> 1) * 16384 + r * 128 +              \
                                         ((((kk << 2) + lslot) ^ lswz) << 4));      \
    }
#define MFMA_Q(mh, nh)                                                              \
  __builtin_amdgcn_s_setprio(1);                                                    \
  _Pragma("unroll")                                                                 \
  for (int mt = 0; mt < 4; ++mt)                                                    \
    _Pragma("unroll")                                                               \
    for (int nt = 0; nt < 2; ++nt)                                                  \
      _Pragma("unroll")                                                             \
      for (int kk = 0; kk < 2; ++kk)                                                \
        acc[(mh) * 4 + mt][(nh) * 2 + nt] = __builtin_amdgcn_mfma_f32_16x16x32_bf16(\
            af[mt][kk], bfr[nh][nt][kk], acc[(mh) * 4 + mt][(nh) * 2 + nt], 0, 0, 0);\
  __builtin_amdgcn_s_setprio(0);
#define LGKM0 asm volatile("s_waitcnt lgkmcnt(0)" ::: "memory");                    \
              __builtin_amdgcn_sched_barrier(0);
#define BAR   __builtin_amdgcn_s_barrier();

  // prologue: tile0 (4 halves) + A0(t1)
  STAGEH(0, 0, 0) STAGEH(0, 1, 0) STAGEH(0, 2, 0) STAGEH(0, 3, 0)
  STAGEH(1, 0, 1)

  for (int kt = 0; kt < NT; ++kt) {
    const int c = kt & 1;
    // ---- phase 0 (quadrant m0,n0) ----
    if (kt + 1 < NT) STAGEH(c ^ 1, 1, kt + 1)
    asm volatile("s_waitcnt vmcnt(4)" ::: "memory");
    __builtin_amdgcn_sched_barrier(0);
    BAR
    __builtin_amdgcn_sched_barrier(0);
    READ_A(c, 0)
    READ_B(c, 0)
    LGKM0
    MFMA_Q(0, 0)
    BAR
    // ---- phase 1 (m0,n1) ----
    READ_B(c, 1)
    if (kt + 1 < NT) STAGEH(c ^ 1, 2, kt + 1)
    LGKM0
    MFMA_Q(0, 1)
    BAR
    // ---- phase 2 (m1,n0) ----
    READ_A(c, 1)
    if (kt + 1 < NT) STAGEH(c ^ 1, 3, kt + 1)
    LGKM0
    MFMA_Q(1, 0)
    BAR
    // ---- phase 3 (m1,n1) -- no new ds_reads; stage A0(t+2) into buf c ----
    if (kt + 2 < NT) STAGEH(c, 0, kt + 2)
    MFMA_Q(1, 1)
    // no end barrier: next iteration's ph0 vmcnt+barrier covers it
  }
#undef STAGEH
#undef READ_A
#undef READ_B
#undef MFMA_Q
#undef LGKM0
#undef BAR

  // ---- epilogue ----
#pragma unroll
  for (int mi = 0; mi < 8; ++mi) {
    const int gmb = m0 + wr * 128 + mi * 16 + (lane >> 4) * 4;
#pragma unroll
    for (int ni = 0; ni < 4; ++ni) {
      const int gn = n0 + wc * 64 + ni * 16 + (lane & 15);
#pragma unroll
      for (int r = 0; r < 4; ++r) {
        float v = acc[mi][ni][r];
        if (EPI == 0) {
          outF[(size_t)(gmb + r) * DM + gn] = v;
        } else {
          const int row = gmb + r;
          const int b = row >> 11, s = row & (SEQ - 1);
          const int gnl = gn & 1023;
          const int h = gnl >> 6, dd = gnl & 63;
          if (z < 2) {
            float p = __shfl_xor(v, 1);
            const float2 cs = tab[(s << 5) + (dd >> 1)];
            float o = ((lane & 1) == 0) ? (v * cs.x - p * cs.y) : (p * cs.y + v * cs.x);
            if (z == 0) o *= 0.18033688011112042f;  // 0.125 * log2(e)
            u16* dst = z ? Kh : Qh;
            dst[((size_t)((b * NH + h) * SEQ + s) << 6) + dd] = f2bf(o);
          } else {
            Vt[((size_t)((b * NH + h) << 6) + dd) * SEQ + s] = f2bf(v);
          }
        }
      }
    }
  }
}

// Flash attention, causal, log2-domain softmax, SWAPPED-OPERAND 32x32x16 MFMA
// (in-register softmax) + block-shared double-buffered LDS K/V staging via
// global_load_lds with XOR swizzle. Grid 1024 = 64 bh x 16 ranks; block owns
// 128 q-rows (4 waves x 32); one barrier per K-tile.
__global__ __launch_bounds__(256)
void attn_k(const u16* __restrict__ Qh, const u16* __restrict__ Kh,
            const u16* __restrict__ Vt, u16* __restrict__ AO) {
  __shared__ u16 lsK[2][64 * 64];
  __shared__ u16 lsV[2][64 * 64];
  const int t = threadIdx.x, lane = t & 63, w = t >> 6;
  const int hiL = lane >> 5;
  const int q31 = lane & 31;
  const int bid = blockIdx.x;
  const int bh = bid & 63, b = bh >> 4, h = bh & 15;
  const int chunk_blk = 15 - (bid >> 6);      // heavy-first
  const int qb_blk = chunk_blk * 128;
  const int tendB = (qb_blk + 127) >> 6;
  const int qbase = qb_blk + w * 32;
  const int tendW = (qbase + 31) >> 6;
  const u16* Qp = Qh + (size_t)bh * SEQ * 64;
  const u16* Kp = Kh + (size_t)bh * SEQ * 64;
  const u16* Vp = Vt + (size_t)bh * 64 * SEQ;

  bf16x8 qa[4];
#pragma unroll
  for (int kc = 0; kc < 4; ++kc)
    qa[kc] = *(const bf16x8*)(Qp + (size_t)(qbase + q31) * 64 + kc * 16 + hiL * 8);

  f32x16 O0 = {}, O1 = {};
  float m = -1e30f, l = 0.f;

#define STAGE(bf, kt_)                                                                  \
  {                                                                                     \
    const int k0s = (kt_) * 64;                                                         \
    _Pragma("unroll")                                                                   \
    for (int hh = 0; hh < 2; ++hh) {                                                    \
      const int idx = hh * 256 + t;                                                     \
      const int row = idx >> 3;                                                         \
      const int cb = ((idx & 7) << 4) ^ ((row & 7) << 4);                               \
      __builtin_amdgcn_global_load_lds((const as1_u32*)(Kp + (size_t)(k0s + row) * 64 + (cb >> 1)), \
                                       (as3_u32*)((char*)&lsK[bf][0] + idx * 16), 16, 0, 0); \
      __builtin_amdgcn_global_load_lds((const as1_u32*)(Vp + (size_t)row * SEQ + k0s + (cb >> 1)), \
                                       (as3_u32*)((char*)&lsV[bf][0] + idx * 16), 16, 0, 0); \
    }                                                                                   \
  }

  STAGE(0, 0);
  __syncthreads();
  int cur = 0;

  for (int kt = 0; kt <= tendB; ++kt) {
    if (kt < tendB) STAGE(cur ^ 1, kt + 1);

    if (kt <= tendW) {
      const int k0 = kt * 64;
      const int swz = (q31 & 7) << 4;

      f32x16 S0 = {}, S1 = {};
#pragma unroll
      for (int kc = 0; kc < 4; ++kc) {
        const int cb = (kc * 32 + hiL * 16) ^ swz;
        bf16x8 ka = *(const bf16x8*)&lsK[cur][q31 * 64 + (cb >> 1)];
        S0 = __builtin_amdgcn_mfma_f32_32x32x16_bf16(ka, qa[kc], S0, 0, 0, 0);
      }
#pragma unroll
      for (int kc = 0; kc < 4; ++kc) {
        const int cb = (kc * 32 + hiL * 16) ^ swz;
        bf16x8 ka = *(const bf16x8*)&lsK[cur][(32 + q31) * 64 + (cb >> 1)];
        S1 = __builtin_amdgcn_mfma_f32_32x32x16_bf16(ka, qa[kc], S1, 0, 0, 0);
      }

      if (kt == tendW) {
        const int qg = qbase + q31;
#pragma unroll
        for (int r = 0; r < 16; ++r) {
          const int kg = k0 + (r & 3) + 8 * (r >> 2) + 4 * hiL;
          S0[r] = (kg > qg) ? -1e30f : S0[r];
          S1[r] = (kg + 32 > qg) ? -1e30f : S1[r];
        }
      }

      float vmax = -1e30f;
#pragma unroll
      for (int r = 0; r < 16; ++r) {
        vmax = fmaxf(vmax, S0[r]);
        vmax = fmaxf(vmax, S1[r]);
      }
      vmax = fmaxf(vmax, __shfl_xor(vmax, 32));

      if (vmax > m + 7.f) {
        const float al = exp2f(m - vmax);
        m = vmax; l *= al;
#pragma unroll
        for (int r = 0; r < 16; ++r) { O0[r] *= al; O1[r] *= al; }
      }

      float rs = 0.f;
#pragma unroll
      for (int r = 0; r < 16; ++r) {
        const float p0 = exp2f(S0[r] - m);
        const float p1 = exp2f(S1[r] - m);
        S0[r] = p0; S1[r] = p1;
        rs += p0 + p1;
      }
      l += rs;

      bf16x8 pb[4];
#define PACKKC(SV, kb, OUT)                                                         \
      {                                                                             \
        u32 qL0, qL1, qH0, qH1;                                                     \
        asm("v_cvt_pk_bf16_f32 %0, %1, %2" : "=v"(qL0) : "v"(SV[8*(kb)+0]), "v"(SV[8*(kb)+1])); \
        asm("v_cvt_pk_bf16_f32 %0, %1, %2" : "=v"(qL1) : "v"(SV[8*(kb)+2]), "v"(SV[8*(kb)+3])); \
        asm("v_cvt_pk_bf16_f32 %0, %1, %2" : "=v"(qH0) : "v"(SV[8*(kb)+4]), "v"(SV[8*(kb)+5])); \
        asm("v_cvt_pk_bf16_f32 %0, %1, %2" : "=v"(qH1) : "v"(SV[8*(kb)+6]), "v"(SV[8*(kb)+7])); \
        const u32 sA = hiL ? qL0 : qH0;                                             \
        const u32 sB = hiL ? qL1 : qH1;                                             \
        const u32 rA = (u32)__shfl_xor((int)sA, 32);                                \
        const u32 rB = (u32)__shfl_xor((int)sB, 32);                                \
        union { u32 wds[4]; bf16x8 v; } uu;                                         \
        uu.wds[0] = hiL ? rA : qL0;                                                 \
        uu.wds[1] = hiL ? rB : qL1;                                                 \
        uu.wds[2] = hiL ? qH0 : rA;                                                 \
        uu.wds[3] = hiL ? qH1 : rB;                                                 \
        OUT = uu.v;                                                                 \
      }
      PACKKC(S0, 0, pb[0])
      PACKKC(S0, 1, pb[1])
      PACKKC(S1, 0, pb[2])
      PACKKC(S1, 1, pb[3])
#undef PACKKC

#pragma unroll
      for (int kc = 0; kc < 4; ++kc) {
        const int cb = (kc * 32 + hiL * 16) ^ swz;
        bf16x8 va0 = *(const bf16x8*)&lsV[cur][q31 * 64 + (cb >> 1)];
        bf16x8 va1 = *(const bf16x8*)&lsV[cur][(32 + q31) * 64 + (cb >> 1)];
        O0 = __builtin_amdgcn_mfma_f32_32x32x16_bf16(va0, pb[kc], O0, 0, 0, 0);
        O1 = __builtin_amdgcn_mfma_f32_32x32x16_bf16(va1, pb[kc], O1, 0, 0, 0);
      }
    }

    __syncthreads();
    cur ^= 1;
  }

  l += __shfl_xor(l, 32);
  const float inv = 1.f / l;
  const int s = qbase + q31;
  u16* dst = AO + ((size_t)(b * SEQ + s) * NH + h) * 64;
#pragma unroll
  for (int rp = 0; rp < 8; ++rp) {
    const int r = rp * 2;
    const int d = (r & 3) + 8 * (r >> 2) + 4 * hiL;
    u32 w0, w1;
    asm("v_cvt_pk_bf16_f32 %0, %1, %2" : "=v"(w0) : "v"(O0[r] * inv), "v"(O0[r + 1] * inv));
    asm("v_cvt_pk_bf16_f32 %0, %1, %2" : "=v"(w1) : "v"(O1[r] * inv), "v"(O1[r + 1] * inv));
    *reinterpret_cast<u32*>(dst + d) = w0;
    *reinterpret_cast<u32*>(dst + 32 + d) = w1;
  }
}

extern "C" void kernel_launch(void* const* d_in, const int* in_sizes, int n_in,
                              void* d_out, int out_size, void* d_ws, size_t ws_size,
                              hipStream_t stream) {
  const float* x  = (const float*)d_in[0];
  const int*   pos = (const int*)d_in[1];
  const float* Wq = (const float*)d_in[2];
  const float* Wk = (const float*)d_in[3];
  const float* Wv = (const float*)d_in[4];
  const float* Wo = (const float*)d_in[5];
  float* out = (float*)d_out;
  char* ws = (char*)d_ws;
  const size_t MB = 1024 * 1024;
  if (ws_size < 73 * MB) return;  // refuse to scribble OOB

  u16* xb  = (u16*)(ws);             // 16MB; re-used as AO after QKV proj
  u16* wqb = (u16*)(ws + 16 * MB);
  u16* wkb = (u16*)(ws + 18 * MB);
  u16* wvb = (u16*)(ws + 20 * MB);
  u16* wob = (u16*)(ws + 22 * MB);
  u16* Qh  = (u16*)(ws + 24 * MB);
  u16* Kh  = (u16*)(ws + 40 * MB);
  u16* Vt  = (u16*)(ws + 56 * MB);
  float2* tab = (float2*)(ws + 72 * MB);
  u16* AO = xb;

  cast_bf16_k<<<(MTOT * DM / 4) / 256, 256, 0, stream>>>(x, xb, MTOT * DM / 4);
  cast_bf16_k<<<(DM * DM / 4) / 256, 256, 0, stream>>>(Wq, wqb, DM * DM / 4);
  cast_bf16_k<<<(DM * DM / 4) / 256, 256, 0, stream>>>(Wk, wkb, DM * DM / 4);
  cast_bf16_k<<<(DM * DM / 4) / 256, 256, 0, stream>>>(Wv, wvb, DM * DM / 4);
  cast_bf16_k<<<(DM * DM / 4) / 256, 256, 0, stream>>>(Wo, wob, DM * DM / 4);
  rope_tab_k<<<(SEQ * 32) / 256, 256, 0, stream>>>(pos, tab);

  // QKV fused over N=3072 (z = n0>>10): grid 12 x 32
  gemm8<1><<<dim3(12, 32), 512, 0, stream>>>(xb, wqb, wkb, wvb, nullptr, Qh, Kh, Vt, tab);
  attn_k<<<dim3(1024), 256, 0, stream>>>(Qh, Kh, Vt, AO);
  // Wo: grid 4 x 32
  gemm8<0><<<dim3(4, 32), 512, 0, stream>>>(AO, wob, wob, wob, out, nullptr, nullptr, nullptr, nullptr);
}

// Round 10
// 222.422 us; speedup vs baseline: 1.0842x; 1.0842x over previous
//
#include <hip/hip_runtime.h>

#define SEQ   2048
#define BATCH 4
#define NH    16
#define DM    1024
#define MTOT  (BATCH*SEQ)   // 8192

typedef unsigned short u16;
typedef unsigned int   u32;
typedef __attribute__((ext_vector_type(8)))  __bf16 bf16x8;
typedef __attribute__((ext_vector_type(4)))  float  f32x4;
typedef __attribute__((ext_vector_type(16))) float  f32x16;
typedef __attribute__((address_space(1))) u32 as1_u32;
typedef __attribute__((address_space(3))) u32 as3_u32;

__device__ __forceinline__ u16 f2bf(float f) {
  union { float f; u32 u; } c; c.f = f;
  return (u16)((c.u + 0x7fffu + ((c.u >> 16) & 1u)) >> 16);
}

// Fused front-end: all four weight casts + x cast + RoPE table in ONE launch.
__global__ __launch_bounds__(256)
void prep_k(const float* __restrict__ x,  const float* __restrict__ Wq,
            const float* __restrict__ Wk, const float* __restrict__ Wv,
            const float* __restrict__ Wo, const int* __restrict__ pos,
            u16* __restrict__ xb,  u16* __restrict__ wqb, u16* __restrict__ wkb,
            u16* __restrict__ wvb, u16* __restrict__ wob, float2* __restrict__ tab) {
  const int NX4 = MTOT * DM / 4;   // 2097152
  const int NW4 = DM * DM / 4;     // 262144
  const int i = blockIdx.x * blockDim.x + threadIdx.x;
  int j = i;
  const float* src = nullptr; u16* dst = nullptr;
  if (j < NX4) { src = x; dst = xb; }
  else {
    j -= NX4;
    if (j < NW4) { src = Wq; dst = wqb; }
    else if (j < 2 * NW4) { src = Wk; dst = wkb; j -= NW4; }
    else if (j < 3 * NW4) { src = Wv; dst = wvb; j -= 2 * NW4; }
    else if (j < 4 * NW4) { src = Wo; dst = wob; j -= 3 * NW4; }
    else {
      j -= 4 * NW4;
      if (j < SEQ * 32) {
        const int s = j >> 5, jj = j & 31;
        const float p = (float)pos[s];
        const float fr = powf(10000.f, -(float)jj / 32.f);
        tab[j] = make_float2(cosf(p * fr), sinf(p * fr));
      }
      return;
    }
  }
  float4 v = reinterpret_cast<const float4*>(src)[j];
  ushort4 o;
  o.x = f2bf(v.x); o.y = f2bf(v.y); o.z = f2bf(v.z); o.w = f2bf(v.w);
  reinterpret_cast<ushort4*>(dst)[j] = o;
}

// C = A @ Bt^T.  A: [M,1024] bf16 row-major. Bt: [1024,1024] bf16 row-major ([N][K]).
// EPI 0: fp32 store to outF. EPI 1: z=0/1 -> RoPE -> Qh/Kh [B,H,S,64]; z=2 -> Vt [B,H,64,S].
// Q additionally scaled by 0.125*log2(e) so attention can use exp2 with no extra mult.
// (2-phase 128x128 m97-structure: ~490 TF at this shape. 8-phase 256^2 port was
// SLOWER here -- R9: 117us, 1.5 blocks/CU rounds + K=1024 too short. Reverted.)
template<int EPI>
__global__ __launch_bounds__(256)
void gemm_bt(const u16* __restrict__ A,
             const u16* __restrict__ B0, const u16* __restrict__ B1, const u16* __restrict__ B2,
             float* __restrict__ outF,
             u16* __restrict__ Qh, u16* __restrict__ Kh, u16* __restrict__ Vt,
             const float2* __restrict__ tab) {
  const int K = DM, N = DM;
  __shared__ u16 lsA[128 * 32];
  __shared__ u16 lsB[128 * 32];
  const int t = threadIdx.x;
  const int lane = t & 63;
  const int wid = t >> 6;
  const int wr = wid >> 1, wc = wid & 1;
  const int m0 = blockIdx.y * 128, n0 = blockIdx.x * 128;
  const int z = blockIdx.z;
  const u16* Bt = (z == 0) ? B0 : (z == 1 ? B1 : B2);

  f32x4 acc[4][4] = {};

  const int srow = t >> 2;
  const int scol = (t & 3) * 8;
  const u16* gA = A + (size_t)(m0 + srow) * K + scol;
  const u16* gB = Bt + (size_t)(n0 + srow) * K + scol;
  const u32 lo = (u32)t * 16u;

  for (int kt = 0; kt < K; kt += 32) {
    __builtin_amdgcn_global_load_lds((const as1_u32*)(gA + kt),
                                     (as3_u32*)((char*)lsA + lo), 16, 0, 0);
    __builtin_amdgcn_global_load_lds((const as1_u32*)(gA + (size_t)64 * K + kt),
                                     (as3_u32*)((char*)lsA + 4096 + lo), 16, 0, 0);
    __builtin_amdgcn_global_load_lds((const as1_u32*)(gB + kt),
                                     (as3_u32*)((char*)lsB + lo), 16, 0, 0);
    __builtin_amdgcn_global_load_lds((const as1_u32*)(gB + (size_t)64 * K + kt),
                                     (as3_u32*)((char*)lsB + 4096 + lo), 16, 0, 0);
    __syncthreads();
    bf16x8 af[4], bfr[4];
#pragma unroll
    for (int mt = 0; mt < 4; ++mt)
      af[mt] = *(const bf16x8*)&lsA[(wr * 64 + mt * 16 + (lane & 15)) * 32 + (lane >> 4) * 8];
#pragma unroll
    for (int nt = 0; nt < 4; ++nt)
      bfr[nt] = *(const bf16x8*)&lsB[(wc * 64 + nt * 16 + (lane & 15)) * 32 + (lane >> 4) * 8];
#pragma unroll
    for (int mt = 0; mt < 4; ++mt)
#pragma unroll
      for (int nt = 0; nt < 4; ++nt)
        acc[mt][nt] = __builtin_amdgcn_mfma_f32_16x16x32_bf16(af[mt], bfr[nt], acc[mt][nt], 0, 0, 0);
    __syncthreads();
  }

#pragma unroll
  for (int mt = 0; mt < 4; ++mt) {
    const int gmb = m0 + wr * 64 + mt * 16 + (lane >> 4) * 4;
#pragma unroll
    for (int nt = 0; nt < 4; ++nt) {
      const int gn = n0 + wc * 64 + nt * 16 + (lane & 15);
#pragma unroll
      for (int r = 0; r < 4; ++r) {
        float v = acc[mt][nt][r];
        if (EPI == 0) {
          outF[(size_t)(gmb + r) * N + gn] = v;
        } else {
          const int row = gmb + r;
          const int b = row >> 11, s = row & (SEQ - 1);
          const int h = gn >> 6, dd = gn & 63;
          if (z < 2) {
            float p = __shfl_xor(v, 1);
            const float2 cs = tab[(s << 5) + (dd >> 1)];
            float o = ((lane & 1) == 0) ? (v * cs.x - p * cs.y) : (p * cs.y + v * cs.x);
            if (z == 0) o *= 0.18033688011112042f;  // 0.125 * log2(e)
            u16* dst = z ? Kh : Qh;
            dst[((size_t)((b * NH + h) * SEQ + s) << 6) + dd] = f2bf(o);
          } else {
            Vt[((size_t)((b * NH + h) << 6) + dd) * SEQ + s] = f2bf(v);
          }
        }
      }
    }
  }
}

// Flash attention, causal, log2-domain softmax, SWAPPED-OPERAND 32x32x16 MFMA
// (in-register softmax) + block-shared LDS K/V staging via global_load_lds with
// XOR swizzle. NEW (T4): 2-tile-deep staging, counted vmcnt(4) at tile top (never
// drains the in-flight stage), raw s_barriers, STAGE(t+2) after the post-compute
// barrier (write-after-read safe: MFMA consumption forces each wave's ds_reads to
// retire before it reaches the barrier). Grid 1024 = 64 bh x 16 ranks; block owns
// 128 q-rows (4 waves x 32).
__global__ __launch_bounds__(256)
void attn_k(const u16* __restrict__ Qh, const u16* __restrict__ Kh,
            const u16* __restrict__ Vt, u16* __restrict__ AO) {
  __shared__ u16 lsK[2][64 * 64];
  __shared__ u16 lsV[2][64 * 64];
  const int t = threadIdx.x, lane = t & 63, w = t >> 6;
  const int hiL = lane >> 5;
  const int q31 = lane & 31;
  const int bid = blockIdx.x;
  const int bh = bid & 63, b = bh >> 4, h = bh & 15;
  const int chunk_blk = 15 - (bid >> 6);      // heavy-first
  const int qb_blk = chunk_blk * 128;
  const int tendB = (qb_blk + 127) >> 6;      // >= 1 always
  const int qbase = qb_blk + w * 32;
  const int tendW = (qbase + 31) >> 6;
  const u16* Qp = Qh + (size_t)bh * SEQ * 64;
  const u16* Kp = Kh + (size_t)bh * SEQ * 64;
  const u16* Vp = Vt + (size_t)bh * 64 * SEQ;

  bf16x8 qa[4];
#pragma unroll
  for (int kc = 0; kc < 4; ++kc)
    qa[kc] = *(const bf16x8*)(Qp + (size_t)(qbase + q31) * 64 + kc * 16 + hiL * 8);

  f32x16 O0 = {}, O1 = {};
  float m = -1e30f, l = 0.f;

  // stage tile kt_ into buffer bf: 4 gload_lds per thread (2 halves x {K,V}).
  // LDS linear dest; global source column pre-swizzled (both-sides rule).
#define STAGE(bf, kt_)                                                                  \
  {                                                                                     \
    const int k0s = (kt_) * 64;                                                         \
    _Pragma("unroll")                                                                   \
    for (int hh = 0; hh < 2; ++hh) {                                                    \
      const int idx = hh * 256 + t;                                                     \
      const int row = idx >> 3;                                                         \
      const int cb = ((idx & 7) << 4) ^ ((row & 7) << 4);                               \
      __builtin_amdgcn_global_load_lds((const as1_u32*)(Kp + (size_t)(k0s + row) * 64 + (cb >> 1)), \
                                       (as3_u32*)((char*)&lsK[bf][0] + idx * 16), 16, 0, 0); \
      __builtin_amdgcn_global_load_lds((const as1_u32*)(Vp + (size_t)row * SEQ + k0s + (cb >> 1)), \
                                       (as3_u32*)((char*)&lsV[bf][0] + idx * 16), 16, 0, 0); \
    }                                                                                   \
  }

  STAGE(0, 0)
  STAGE(1, 1)

  for (int kt = 0; kt <= tendB; ++kt) {
    const int cur = kt & 1;
    // tile kt resident when only the newest STAGE (4 instr) is outstanding
    asm volatile("s_waitcnt vmcnt(4)" ::: "memory");
    __builtin_amdgcn_sched_barrier(0);
    __builtin_amdgcn_s_barrier();

    if (kt <= tendW) {
      const int k0 = kt * 64;
      const int swz = (q31 & 7) << 4;

      f32x16 S0 = {}, S1 = {};
#pragma unroll
      for (int kc = 0; kc < 4; ++kc) {
        const int cb = (kc * 32 + hiL * 16) ^ swz;
        bf16x8 ka = *(const bf16x8*)&lsK[cur][q31 * 64 + (cb >> 1)];
        S0 = __builtin_amdgcn_mfma_f32_32x32x16_bf16(ka, qa[kc], S0, 0, 0, 0);
      }
#pragma unroll
      for (int kc = 0; kc < 4; ++kc) {
        const int cb = (kc * 32 + hiL * 16) ^ swz;
        bf16x8 ka = *(const bf16x8*)&lsK[cur][(32 + q31) * 64 + (cb >> 1)];
        S1 = __builtin_amdgcn_mfma_f32_32x32x16_bf16(ka, qa[kc], S1, 0, 0, 0);
      }

      if (kt == tendW) {
        const int qg = qbase + q31;
#pragma unroll
        for (int r = 0; r < 16; ++r) {
          const int kg = k0 + (r & 3) + 8 * (r >> 2) + 4 * hiL;
          S0[r] = (kg > qg) ? -1e30f : S0[r];
          S1[r] = (kg + 32 > qg) ? -1e30f : S1[r];
        }
      }

      float vmax = -1e30f;
#pragma unroll
      for (int r = 0; r < 16; ++r) {
        vmax = fmaxf(vmax, S0[r]);
        vmax = fmaxf(vmax, S1[r]);
      }
      vmax = fmaxf(vmax, __shfl_xor(vmax, 32));

      if (vmax > m + 7.f) {    // defer-max (T13), log2 domain
        const float al = exp2f(m - vmax);
        m = vmax; l *= al;
#pragma unroll
        for (int r = 0; r < 16; ++r) { O0[r] *= al; O1[r] *= al; }
      }

      float rs = 0.f;
#pragma unroll
      for (int r = 0; r < 16; ++r) {
        const float p0 = exp2f(S0[r] - m);
        const float p1 = exp2f(S1[r] - m);
        S0[r] = p0; S1[r] = p1;
        rs += p0 + p1;
      }
      l += rs;

      bf16x8 pb[4];
#define PACKKC(SV, kb, OUT)                                                         \
      {                                                                             \
        u32 qL0, qL1, qH0, qH1;                                                     \
        asm("v_cvt_pk_bf16_f32 %0, %1, %2" : "=v"(qL0) : "v"(SV[8*(kb)+0]), "v"(SV[8*(kb)+1])); \
        asm("v_cvt_pk_bf16_f32 %0, %1, %2" : "=v"(qL1) : "v"(SV[8*(kb)+2]), "v"(SV[8*(kb)+3])); \
        asm("v_cvt_pk_bf16_f32 %0, %1, %2" : "=v"(qH0) : "v"(SV[8*(kb)+4]), "v"(SV[8*(kb)+5])); \
        asm("v_cvt_pk_bf16_f32 %0, %1, %2" : "=v"(qH1) : "v"(SV[8*(kb)+6]), "v"(SV[8*(kb)+7])); \
        const u32 sA = hiL ? qL0 : qH0;                                             \
        const u32 sB = hiL ? qL1 : qH1;                                             \
        const u32 rA = (u32)__shfl_xor((int)sA, 32);                                \
        const u32 rB = (u32)__shfl_xor((int)sB, 32);                                \
        union { u32 wds[4]; bf16x8 v; } uu;                                         \
        uu.wds[0] = hiL ? rA : qL0;                                                 \
        uu.wds[1] = hiL ? rB : qL1;                                                 \
        uu.wds[2] = hiL ? qH0 : rA;                                                 \
        uu.wds[3] = hiL ? qH1 : rB;                                                 \
        OUT = uu.v;                                                                 \
      }
      PACKKC(S0, 0, pb[0])
      PACKKC(S0, 1, pb[1])
      PACKKC(S1, 0, pb[2])
      PACKKC(S1, 1, pb[3])
#undef PACKKC

#pragma unroll
      for (int kc = 0; kc < 4; ++kc) {
        const int cb = (kc * 32 + hiL * 16) ^ swz;
        bf16x8 va0 = *(const bf16x8*)&lsV[cur][q31 * 64 + (cb >> 1)];
        bf16x8 va1 = *(const bf16x8*)&lsV[cur][(32 + q31) * 64 + (cb >> 1)];
        O0 = __builtin_amdgcn_mfma_f32_32x32x16_bf16(va0, pb[kc], O0, 0, 0, 0);
        O1 = __builtin_amdgcn_mfma_f32_32x32x16_bf16(va1, pb[kc], O1, 0, 0, 0);
      }
    }

    __builtin_amdgcn_s_barrier();            // all waves done reading buf cur
    if (kt + 2 <= tendB) STAGE(cur, kt + 2)  // overwrite now safe; 2 tiles to land
  }

  l += __shfl_xor(l, 32);
  const float inv = 1.f / l;
  const int s = qbase + q31;
  u16* dst = AO + ((size_t)(b * SEQ + s) * NH + h) * 64;
#pragma unroll
  for (int rp = 0; rp < 8; ++rp) {
    const int r = rp * 2;
    const int d = (r & 3) + 8 * (r >> 2) + 4 * hiL;
    u32 w0, w1;
    asm("v_cvt_pk_bf16_f32 %0, %1, %2" : "=v"(w0) : "v"(O0[r] * inv), "v"(O0[r + 1] * inv));
    asm("v_cvt_pk_bf16_f32 %0, %1, %2" : "=v"(w1) : "v"(O1[r] * inv), "v"(O1[r + 1] * inv));
    *reinterpret_cast<u32*>(dst + d) = w0;
    *reinterpret_cast<u32*>(dst + 32 + d) = w1;
  }
}

extern "C" void kernel_launch(void* const* d_in, const int* in_sizes, int n_in,
                              void* d_out, int out_size, void* d_ws, size_t ws_size,
                              hipStream_t stream) {
  const float* x  = (const float*)d_in[0];
  const int*   pos = (const int*)d_in[1];
  const float* Wq = (const float*)d_in[2];
  const float* Wk = (const float*)d_in[3];
  const float* Wv = (const float*)d_in[4];
  const float* Wo = (const float*)d_in[5];
  float* out = (float*)d_out;
  char* ws = (char*)d_ws;
  const size_t MB = 1024 * 1024;
  if (ws_size < 73 * MB) return;  // refuse to scribble OOB

  u16* xb  = (u16*)(ws);             // 16MB; re-used as AO after QKV proj
  u16* wqb = (u16*)(ws + 16 * MB);
  u16* wkb = (u16*)(ws + 18 * MB);
  u16* wvb = (u16*)(ws + 20 * MB);
  u16* wob = (u16*)(ws + 22 * MB);
  u16* Qh  = (u16*)(ws + 24 * MB);
  u16* Kh  = (u16*)(ws + 40 * MB);
  u16* Vt  = (u16*)(ws + 56 * MB);
  float2* tab = (float2*)(ws + 72 * MB);
  u16* AO = xb;

  const int NPREP = MTOT * DM / 4 + 4 * (DM * DM / 4) + SEQ * 32;
  prep_k<<<(NPREP + 255) / 256, 256, 0, stream>>>(x, Wq, Wk, Wv, Wo, pos,
                                                  xb, wqb, wkb, wvb, wob, tab);
  gemm_bt<1><<<dim3(8, 64, 3), 256, 0, stream>>>(xb, wqb, wkb, wvb, nullptr, Qh, Kh, Vt, tab);
  attn_k<<<dim3(1024), 256, 0, stream>>>(Qh, Kh, Vt, AO);
  gemm_bt<0><<<dim3(8, 64, 1), 256, 0, stream>>>(AO, wob, wob, wob, out, nullptr, nullptr, nullptr, nullptr);
}